// Round 2
// baseline (267.742 us; speedup 1.0000x reference)
//
#include <hip/hip_runtime.h>
#include <math.h>

// Problem constants (match reference setup_inputs)
constexpr int Bn = 131072;   // batch
constexpr int Fn = 1024;     // features
constexpr int Tn = 100;      // trees
constexpr int Kn = 32;       // features per tree

constexpr int BLOCK = 256;
constexpr int WPB   = BLOCK / 64;   // waves per block = 4
constexpr int GRID  = 1024;         // 4 blocks/CU * 256 CUs; 4096 waves, 32 rows each

using gptr_t = const __attribute__((address_space(1))) void*;
using lptr_t = __attribute__((address_space(3))) void*;

__global__ __launch_bounds__(BLOCK, 4)   // cap VGPR<=128 -> 16 waves/CU
void rf_fwd(const float* __restrict__ x,
            const int*   __restrict__ fidx,
            const float* __restrict__ fthr,
            const float* __restrict__ fw,
            float*       __restrict__ out)
{
    __shared__ float ldsbuf[WPB][2][Fn];   // 32 KB per block: per-wave double buffer

    const int lane  = threadIdx.x & 63;
    const int wid   = threadIdx.x >> 6;
    const int gwave = blockIdx.x * WPB + wid;
    const int nwave = GRID * WPB;

    // Lane handles tree t0 = lane, and t1 = 64+lane when it exists (lane < 36).
    const int  t0   = lane;
    const bool has1 = (64 + lane) < Tn;
    const int  t1   = has1 ? (64 + lane) : lane;   // fallback keeps loads in bounds

    // ---- Packed per-lane tables: u32 = (w & 0xFFFFF000) | (idx*4) ----
    // w truncated to 11 mantissa bits (rel err <= ~5e-4); idx*4 = LDS byte offset.
    uint32_t pk0[Kn], pk1[Kn];
    float bias0 = 0.f, bias1 = 0.f;

#pragma unroll
    for (int k = 0; k < Kn; k += 4) {
        int4   i4 = *(const int4*)  (fidx + t0 * Kn + k);
        float4 wv = *(const float4*)(fw   + t0 * Kn + k);
        float4 th = *(const float4*)(fthr + t0 * Kn + k);
        uint32_t wb0 = __float_as_uint(wv.x) & 0xFFFFF000u;
        uint32_t wb1 = __float_as_uint(wv.y) & 0xFFFFF000u;
        uint32_t wb2 = __float_as_uint(wv.z) & 0xFFFFF000u;
        uint32_t wb3 = __float_as_uint(wv.w) & 0xFFFFF000u;
        pk0[k+0] = wb0 | ((uint32_t)i4.x << 2);
        pk0[k+1] = wb1 | ((uint32_t)i4.y << 2);
        pk0[k+2] = wb2 | ((uint32_t)i4.z << 2);
        pk0[k+3] = wb3 | ((uint32_t)i4.w << 2);
        bias0 += th.x*__uint_as_float(wb0) + th.y*__uint_as_float(wb1)
               + th.z*__uint_as_float(wb2) + th.w*__uint_as_float(wb3);
    }
#pragma unroll
    for (int k = 0; k < Kn; k += 4) {
        int4   i4 = *(const int4*)  (fidx + t1 * Kn + k);
        float4 wv = *(const float4*)(fw   + t1 * Kn + k);
        float4 th = *(const float4*)(fthr + t1 * Kn + k);
        uint32_t wb0 = __float_as_uint(wv.x) & 0xFFFFF000u;
        uint32_t wb1 = __float_as_uint(wv.y) & 0xFFFFF000u;
        uint32_t wb2 = __float_as_uint(wv.z) & 0xFFFFF000u;
        uint32_t wb3 = __float_as_uint(wv.w) & 0xFFFFF000u;
        pk1[k+0] = wb0 | ((uint32_t)i4.x << 2);
        pk1[k+1] = wb1 | ((uint32_t)i4.y << 2);
        pk1[k+2] = wb2 | ((uint32_t)i4.z << 2);
        pk1[k+3] = wb3 | ((uint32_t)i4.w << 2);
        bias1 += th.x*__uint_as_float(wb0) + th.y*__uint_as_float(wb1)
               + th.z*__uint_as_float(wb2) + th.w*__uint_as_float(wb3);
    }

    float* buf0 = &ldsbuf[wid][0][0];
    float* buf1 = &ldsbuf[wid][1][0];

    // Stage one 4KB row: 4 issues of 16B/lane (1KB each), wave-uniform LDS base,
    // per-lane global address. Linear dest order matches lane order (G21 ok).
    auto stage = [&](const float* src, float* dst) {
#pragma unroll
        for (int c = 0; c < 4; ++c) {
            __builtin_amdgcn_global_load_lds(
                (gptr_t)(src + c * 256 + lane * 4),
                (lptr_t)(dst + c * 256),
                16, 0, 0);
        }
    };

    int row = gwave;
    if (row < Bn) stage(x + (size_t)row * Fn, buf0);

    float* cur = buf0;
    float* nxt = buf1;

    for (; row < Bn; row += nwave) {
        const int nrow = row + nwave;          // wave-uniform
        if (nrow < Bn) {
            stage(x + (size_t)nrow * Fn, nxt);
            // FIFO: wait until only the 4 newest (next-buf) loads remain:
            // current buffer is complete.
            asm volatile("s_waitcnt vmcnt(4)" ::: "memory");
        } else {
            asm volatile("s_waitcnt vmcnt(0)" ::: "memory");
        }

        const char* curb = (const char*)cur;
        float acc0 = 0.f, acc1 = 0.f;
#pragma unroll
        for (int k = 0; k < Kn; ++k) {
            const uint32_t u0 = pk0[k];
            const uint32_t u1 = pk1[k];
            const float v0 = *(const float*)(curb + (u0 & 0xFFFu));
            const float v1 = *(const float*)(curb + (u1 & 0xFFFu));
            acc0 = fmaf(v0, __uint_as_float(u0 & 0xFFFFF000u), acc0);
            acc1 = fmaf(v1, __uint_as_float(u1 & 0xFFFFF000u), acc1);
        }

        const float ws0 = acc0 - bias0;
        const float ws1 = acc1 - bias1;
        const float p0  = 1.f / (1.f + __expf(-ws0));
        const float p1  = 1.f / (1.f + __expf(-ws1));

        float s = p0 + (has1 ? p1 : 0.f);
#pragma unroll
        for (int d = 1; d < 64; d <<= 1) s += __shfl_xor(s, d, 64);

        if (lane == 0) {
            const float pm = s * (1.0f / Tn);
            *(float2*)(out + (size_t)row * 2) = make_float2(1.0f - pm, pm);
        }

        float* tmp = cur; cur = nxt; nxt = tmp;
    }
}

extern "C" void kernel_launch(void* const* d_in, const int* in_sizes, int n_in,
                              void* d_out, int out_size, void* d_ws, size_t ws_size,
                              hipStream_t stream) {
    const float* x    = (const float*)d_in[0];
    const int*   fidx = (const int*)  d_in[1];
    const float* fthr = (const float*)d_in[2];
    const float* fw   = (const float*)d_in[3];
    float*       out  = (float*)d_out;

    rf_fwd<<<GRID, BLOCK, 0, stream>>>(x, fidx, fthr, fw, out);
}

// Round 3
// 168.302 us; speedup vs baseline: 1.5908x; 1.5908x over previous
//
#include <hip/hip_runtime.h>
#include <math.h>

// Problem constants (match reference setup_inputs)
constexpr int Bn = 131072;   // batch
constexpr int Fn = 1024;     // features (= GEMM K)
constexpr int Tn = 100;      // trees
constexpr int Kn = 32;       // features per tree

constexpr int TP = 112;            // trees padded to 7*16 (GEMM N)
constexpr int NF = TP / 16;        // 7 B-fragments per wave
constexpr int BK = 32;             // K per tile (one MFMA K-step)
constexpr int NT = Fn / BK;        // 32 K-tiles
constexpr int BM = 128;            // rows per block
constexpr int MW = 32;             // rows per wave (2 A-fragments)
constexpr int BLOCK = 256;
constexpr int GRID = Bn / BM;      // 1024 blocks (exactly 4/CU)

typedef __attribute__((ext_vector_type(8))) short bf16x8;
typedef __attribute__((ext_vector_type(4))) float f32x4;

using gptr_t = const __attribute__((address_space(1))) void*;
using lptr_t = __attribute__((address_space(3))) void*;

// fp32 -> bf16, round-to-nearest-even (truncation's one-sided bias would
// accumulate linearly over K=32 terms; RN keeps ws error ~0.005 RMS)
__device__ inline unsigned short f2bf(float f) {
    uint32_t u = __float_as_uint(f);
    return (unsigned short)((u + 0x7FFFu + ((u >> 16) & 1u)) >> 16);
}

// ---------------------------------------------------------------------------
// Prep: build W_T bf16 [TP][Fn] (row t = tree t's dense weight row) + bias[TP]
// in workspace. One block per tree row: zero the 2KB row, barrier, scatter the
// 32 weights (replace=False sampling -> no duplicate idx within a tree).
// ---------------------------------------------------------------------------
__global__ __launch_bounds__(64)
void rf_prep(const int* __restrict__ fidx, const float* __restrict__ fthr,
             const float* __restrict__ fw,
             unsigned short* __restrict__ wt, float* __restrict__ bias)
{
    const int t    = blockIdx.x;     // 0..111
    const int lane = threadIdx.x;    // 0..63

    // zero this tree's 1024 bf16 (2 KB): 64 lanes x 32 B
    int4 z = make_int4(0, 0, 0, 0);
    int4* rowp = (int4*)(wt + (size_t)t * Fn);
    rowp[lane * 2 + 0] = z;
    rowp[lane * 2 + 1] = z;
    __syncthreads();

    float bsum = 0.f;
    if (t < Tn && lane < Kn) {
        const int   idx = fidx[t * Kn + lane];
        const float w   = fw[t * Kn + lane];
        const float th  = fthr[t * Kn + lane];
        wt[(size_t)t * Fn + idx] = f2bf(w);
        bsum = th * w;
    }
#pragma unroll
    for (int d = 1; d < 64; d <<= 1) bsum += __shfl_xor(bsum, d, 64);
    if (lane == 0) bias[t] = (t < Tn) ? bsum : 0.f;
}

// ---------------------------------------------------------------------------
// Main GEMM: C[131072, 112] = x(fp32->bf16) @ W_T^T, fused sigmoid+mean.
// A staged fp32 via global_load_lds with XOR-swizzled SOURCE (linear LDS dest,
// G21 both-sides rule): phys_chunk16 = logical_chunk16 ^ (row & 7).
// B fragments read straight from L2-resident W_T.
// ---------------------------------------------------------------------------
__global__ __launch_bounds__(BLOCK)
void rf_gemm(const float* __restrict__ x,
             const unsigned short* __restrict__ wt,
             const float* __restrict__ bias,
             float* __restrict__ out)
{
    __shared__ float lds[2][BM * BK];   // 2 x 16 KB

    const int lane = threadIdx.x & 63;
    const int wid  = threadIdx.x >> 6;
    const int rb   = blockIdx.x * BM;

    // Staging constants: wave w, instr i covers rows (w*4+i)*8..+7 (1 KB).
    // Lane writes LDS bytes win*1024 + lane*16 -> row = win*8 + (lane>>3),
    // phys chunk = lane&7, so global source chunk = (lane&7) ^ (row&7).
    const int s_row = lane >> 3;              // row within 8-row window
    const int s_c16 = (lane & 7) ^ s_row;     // pre-swizzled logical chunk

    // A-read constants: row_local&7 == lane&7 for all fragments here.
    const int a_rl  = lane & 15;
    const int a_xor = lane & 7;
    const int a_cb  = (lane >> 4) * 2;        // logical 16B chunk (0..7 per row)

    f32x4 acc[2][NF];
#pragma unroll
    for (int m = 0; m < 2; ++m)
#pragma unroll
        for (int f = 0; f < NF; ++f) acc[m][f] = (f32x4){0.f, 0.f, 0.f, 0.f};

    auto stage = [&](int t, int bsel) {
#pragma unroll
        for (int i = 0; i < 4; ++i) {
            const int win = wid * 4 + i;                  // 0..15
            const int row = win * 8 + s_row;              // 0..127
            const float* src = x + (size_t)(rb + row) * Fn + t * BK + s_c16 * 4;
            float* dst = &lds[bsel][win * 256];           // wave-uniform base
            __builtin_amdgcn_global_load_lds((gptr_t)src, (lptr_t)dst, 16, 0, 0);
        }
    };

    stage(0, 0);
    __syncthreads();   // compiler emits vmcnt(0) drain before s_barrier

    for (int t = 0; t < NT; ++t) {
        const int cur = t & 1;
        if (t + 1 < NT) stage(t + 1, cur ^ 1);   // prefetch next tile

        // B fragments: lane reads W_T[f*16 + (lane&15)][t*32 + (lane>>4)*8 ..+7]
        bf16x8 bfr[NF];
#pragma unroll
        for (int f = 0; f < NF; ++f) {
            const unsigned short* bp =
                wt + (size_t)(f * 16 + a_rl) * Fn + t * BK + (lane >> 4) * 8;
            bfr[f] = *(const bf16x8*)bp;
        }

        // A fragments from LDS (swizzled read), fp32 -> bf16
        const float* buf = lds[cur];
        bf16x8 af[2];
#pragma unroll
        for (int m = 0; m < 2; ++m) {
            const int row = wid * MW + m * 16 + a_rl;     // 0..127
            const float* rp = buf + row * BK;
            float4 lo = *(const float4*)(rp + (((a_cb + 0) ^ a_xor) * 4));
            float4 hi = *(const float4*)(rp + (((a_cb + 1) ^ a_xor) * 4));
            bf16x8 v;
            v[0] = (short)f2bf(lo.x); v[1] = (short)f2bf(lo.y);
            v[2] = (short)f2bf(lo.z); v[3] = (short)f2bf(lo.w);
            v[4] = (short)f2bf(hi.x); v[5] = (short)f2bf(hi.y);
            v[6] = (short)f2bf(hi.z); v[7] = (short)f2bf(hi.w);
            af[m] = v;
        }

#pragma unroll
        for (int m = 0; m < 2; ++m)
#pragma unroll
            for (int f = 0; f < NF; ++f)
                acc[m][f] = __builtin_amdgcn_mfma_f32_16x16x32_bf16(
                    af[m], bfr[f], acc[m][f], 0, 0, 0);

        __syncthreads();   // one barrier/tile; implicit full drain = 2-phase
    }

    // ---- epilogue: ws = acc - bias; p = sigmoid(ws); mean over valid trees ----
    const int col = lane & 15;     // C col = lane&15, row = (lane>>4)*4 + reg
    float psum[2][4] = {};
#pragma unroll
    for (int f = 0; f < NF; ++f) {
        const int  n     = f * 16 + col;
        const bool valid = n < Tn;
        const float bv   = bias[n];   // zero-padded
#pragma unroll
        for (int m = 0; m < 2; ++m)
#pragma unroll
            for (int r = 0; r < 4; ++r) {
                const float ws = acc[m][f][r] - bv;
                const float p  = 1.f / (1.f + __expf(-ws));
                if (valid) psum[m][r] += p;
            }
    }
    // reduce over the 16 column-lanes (xor 1,2,4,8 stays within the group)
#pragma unroll
    for (int m = 0; m < 2; ++m)
#pragma unroll
        for (int r = 0; r < 4; ++r)
#pragma unroll
            for (int d = 1; d < 16; d <<= 1)
                psum[m][r] += __shfl_xor(psum[m][r], d, 64);

    const int g = lane >> 4;
#pragma unroll
    for (int m = 0; m < 2; ++m) {
        if (col < 4) {   // lane col==r writes row g*4 + r of this fragment
            const int r   = col;
            const int row = rb + wid * MW + m * 16 + g * 4 + r;
            const float pm = psum[m][r] * (1.0f / Tn);
            *(float2*)(out + (size_t)row * 2) = make_float2(1.0f - pm, pm);
        }
    }
}

extern "C" void kernel_launch(void* const* d_in, const int* in_sizes, int n_in,
                              void* d_out, int out_size, void* d_ws, size_t ws_size,
                              hipStream_t stream) {
    const float* x    = (const float*)d_in[0];
    const int*   fidx = (const int*)  d_in[1];
    const float* fthr = (const float*)d_in[2];
    const float* fw   = (const float*)d_in[3];
    float*       out  = (float*)d_out;

    unsigned short* wt   = (unsigned short*)d_ws;                      // 229376 B
    float*          bias = (float*)((char*)d_ws + (size_t)TP * Fn * 2); // +448 B

    rf_prep<<<TP, 64, 0, stream>>>(fidx, fthr, fw, wt, bias);
    rf_gemm<<<GRID, BLOCK, 0, stream>>>(x, wt, bias, out);
}

// Round 4
// 159.336 us; speedup vs baseline: 1.6804x; 1.0563x over previous
//
#include <hip/hip_runtime.h>
#include <math.h>

// Problem constants (match reference setup_inputs)
constexpr int Bn = 131072;   // batch
constexpr int Fn = 1024;     // features (= GEMM K)
constexpr int Tn = 100;      // trees
constexpr int Kn = 32;       // features per tree

constexpr int TP = 112;            // trees padded to 7*16 (GEMM N)
constexpr int NF = TP / 16;        // 7 B-fragments
constexpr int BK = 64;             // floats per row per stage tile (256 B granule)
constexpr int KS = BK / 32;        // 2 MFMA k-steps per stage tile
constexpr int NT = Fn / BK;        // 16 stage tiles (even -> clean unroll-2)
constexpr int BM = 128;            // rows per block
constexpr int MW = 32;             // rows per wave (wave-private!)
constexpr int BLOCK = 256;
constexpr int GRID = Bn / BM;      // 1024 blocks

typedef __attribute__((ext_vector_type(8))) short bf16x8;
typedef __attribute__((ext_vector_type(4))) float f32x4;

using gptr_t = const __attribute__((address_space(1))) void*;
using lptr_t = __attribute__((address_space(3))) void*;

// fp32 -> bf16 round-to-nearest-even
__device__ inline unsigned short f2bf(float f) {
    uint32_t u = __float_as_uint(f);
    return (unsigned short)((u + 0x7FFFu + ((u >> 16) & 1u)) >> 16);
}

// ---------------------------------------------------------------------------
// Prep: dense W_T bf16 [TP][Fn] + bias[TP] in workspace (unchanged, validated)
// ---------------------------------------------------------------------------
__global__ __launch_bounds__(64)
void rf_prep(const int* __restrict__ fidx, const float* __restrict__ fthr,
             const float* __restrict__ fw,
             unsigned short* __restrict__ wt, float* __restrict__ bias)
{
    const int t    = blockIdx.x;     // 0..111
    const int lane = threadIdx.x;    // 0..63

    int4 z = make_int4(0, 0, 0, 0);
    int4* rowp = (int4*)(wt + (size_t)t * Fn);
    rowp[lane * 2 + 0] = z;
    rowp[lane * 2 + 1] = z;
    __syncthreads();

    float bsum = 0.f;
    if (t < Tn && lane < Kn) {
        const int   idx = fidx[t * Kn + lane];
        const float w   = fw[t * Kn + lane];
        const float th  = fthr[t * Kn + lane];
        wt[(size_t)t * Fn + idx] = f2bf(w);
        bsum = th * w;
    }
#pragma unroll
    for (int d = 1; d < 64; d <<= 1) bsum += __shfl_xor(bsum, d, 64);
    if (lane == 0) bias[t] = (t < Tn) ? bsum : 0.f;
}

// ---------------------------------------------------------------------------
// Barrier-free GEMM: each wave stages & consumes its own 32 rows.
// Pipeline per tile: loadB(t+1) | vmcnt(36) | A ds_read+cvt | lgkmcnt(0) |
//                    stage(t+2) | MFMA.   vmcnt never drains to 0 mid-loop.
// vmcnt bookkeeping (per-wave FIFO): entering tile τ the queue is
//   [stage(τ):8, B(τ):14, stage(τ+1):8] = 30; +loadB(τ+1)=44; vmcnt(36)
//   drains exactly the 8 oldest = stage(τ).  Tail (τ=NT-1): queue is
//   [stage(τ):8, B(τ):14] = 22 -> vmcnt(14).
// ---------------------------------------------------------------------------
__global__ __launch_bounds__(BLOCK, 2)
void rf_gemm(const float* __restrict__ x,
             const unsigned short* __restrict__ wt,
             const float* __restrict__ bias,
             float* __restrict__ out)
{
    __shared__ float lds[2][BM * BK];   // 2 x 32 KB (per-wave 2 x 8 KB slices)

    const int lane = threadIdx.x & 63;
    const int wid  = threadIdx.x >> 6;
    const int rb   = blockIdx.x * BM;

    const int s_r = lane >> 4;          // staging: row within 4-row window
    const int s_p = lane & 15;          // staging: phys 16B chunk
    const int a_L = lane & 15;          // A/B: row-in-frag / swizzle key
    const int a_g = lane >> 4;          // A/B: k-group

    f32x4 acc[2][NF];
#pragma unroll
    for (int m = 0; m < 2; ++m)
#pragma unroll
        for (int f = 0; f < NF; ++f) acc[m][f] = (f32x4){0.f, 0.f, 0.f, 0.f};

    // Stage wave's 32 rows x 256 B for tile t: 8 instr x 1 KB (4 rows each).
    // Source chunk pre-swizzled: c = phys ^ (row & 15); LDS dest linear (G21).
    auto stage = [&](int t, int bsel) {
#pragma unroll
        for (int i = 0; i < 8; ++i) {
            const int row = i * 4 + s_r;                     // 0..31 in wave block
            const int c   = s_p ^ (row & 15);
            const float* src = x + (size_t)(rb + wid * MW + row) * Fn + t * BK + c * 4;
            float* dst = &lds[bsel][wid * (MW * BK) + i * 256];
            __builtin_amdgcn_global_load_lds((gptr_t)src, (lptr_t)dst, 16, 0, 0);
        }
    };

    // B fragments for tile t: 14 x dwordx4 from L2-resident wt.
    auto loadB = [&](int t, bf16x8 (&bfr)[KS][NF]) {
#pragma unroll
        for (int ks = 0; ks < KS; ++ks)
#pragma unroll
            for (int f = 0; f < NF; ++f) {
                const unsigned short* bp =
                    wt + (size_t)(f * 16 + a_L) * Fn + t * BK + ks * 32 + a_g * 8;
                bfr[ks][f] = *(const bf16x8*)bp;
            }
    };

    // A fragments: 8 x ds_read_b128 (swizzled) + cvt to bf16.
    auto readA = [&](int bsel, bf16x8 (&af)[KS][2]) {
        const float* buf = &lds[bsel][wid * (MW * BK)];
#pragma unroll
        for (int ks = 0; ks < KS; ++ks)
#pragma unroll
            for (int m = 0; m < 2; ++m) {
                const float* rp = buf + (m * 16 + a_L) * BK;
                const int c0 = ks * 8 + a_g * 2;
                float4 lo = *(const float4*)(rp + ((c0 ^ a_L) * 4));
                float4 hi = *(const float4*)(rp + (((c0 + 1) ^ a_L) * 4));
                bf16x8 v;
                v[0] = (short)f2bf(lo.x); v[1] = (short)f2bf(lo.y);
                v[2] = (short)f2bf(lo.z); v[3] = (short)f2bf(lo.w);
                v[4] = (short)f2bf(hi.x); v[5] = (short)f2bf(hi.y);
                v[6] = (short)f2bf(hi.z); v[7] = (short)f2bf(hi.w);
                af[ks][m] = v;
            }
    };

    auto mfma_all = [&](bf16x8 (&af)[KS][2], bf16x8 (&bfr)[KS][NF]) {
#pragma unroll
        for (int ks = 0; ks < KS; ++ks)
#pragma unroll
            for (int m = 0; m < 2; ++m)
#pragma unroll
                for (int f = 0; f < NF; ++f)
                    acc[m][f] = __builtin_amdgcn_mfma_f32_16x16x32_bf16(
                        af[ks][m], bfr[ks][f], acc[m][f], 0, 0, 0);
    };

    bf16x8 bA[KS][NF], bB[KS][NF];
    bf16x8 af[KS][2];

    // Prologue, pinned order: [stage(0), B(0), stage(1)] -> queue = 30
    stage(0, 0);
    __builtin_amdgcn_sched_barrier(0);
    loadB(0, bA);
    __builtin_amdgcn_sched_barrier(0);
    stage(1, 1);

    for (int t = 0; t < NT; t += 2) {
        // ---- even: tile t from buf0 / bA ----
        loadB(t + 1, bB);                                   // t+1 <= NT-1 always
        asm volatile("s_waitcnt vmcnt(36)" ::: "memory");   // drain stage(t)
        readA(0, af);
        asm volatile("s_waitcnt lgkmcnt(0)" ::: "memory");  // buf0 reads landed
        if (t + 2 < NT) stage(t + 2, 0);                    // refill freed buf0
        mfma_all(af, bA);                                   // compiler drains B(t)

        // ---- odd: tile t+1 from buf1 / bB ----
        if (t + 2 < NT) {
            loadB(t + 2, bA);
            asm volatile("s_waitcnt vmcnt(36)" ::: "memory");  // drain stage(t+1)
        } else {
            asm volatile("s_waitcnt vmcnt(14)" ::: "memory");  // tail drain
        }
        readA(1, af);
        asm volatile("s_waitcnt lgkmcnt(0)" ::: "memory");
        if (t + 3 < NT) stage(t + 3, 1);
        mfma_all(af, bB);
    }

    // ---- epilogue: ws = acc - bias; p = sigmoid; mean over trees ----
    const int col = lane & 15;     // C col = lane&15, row = (lane>>4)*4 + reg
    float psum[2][4] = {};
#pragma unroll
    for (int f = 0; f < NF; ++f) {
        const int  n     = f * 16 + col;
        const bool valid = n < Tn;
        const float bv   = bias[n];   // zero-padded
#pragma unroll
        for (int m = 0; m < 2; ++m)
#pragma unroll
            for (int r = 0; r < 4; ++r) {
                const float ws = acc[m][f][r] - bv;
                const float p  = 1.f / (1.f + __expf(-ws));
                if (valid) psum[m][r] += p;
            }
    }
#pragma unroll
    for (int m = 0; m < 2; ++m)
#pragma unroll
        for (int r = 0; r < 4; ++r)
#pragma unroll
            for (int d = 1; d < 16; d <<= 1)
                psum[m][r] += __shfl_xor(psum[m][r], d, 64);

    const int g = lane >> 4;
#pragma unroll
    for (int m = 0; m < 2; ++m) {
        if (col < 4) {
            const int r   = col;
            const int row = rb + wid * MW + m * 16 + g * 4 + r;
            const float pm = psum[m][r] * (1.0f / Tn);
            *(float2*)(out + (size_t)row * 2) = make_float2(1.0f - pm, pm);
        }
    }
}

extern "C" void kernel_launch(void* const* d_in, const int* in_sizes, int n_in,
                              void* d_out, int out_size, void* d_ws, size_t ws_size,
                              hipStream_t stream) {
    const float* x    = (const float*)d_in[0];
    const int*   fidx = (const int*)  d_in[1];
    const float* fthr = (const float*)d_in[2];
    const float* fw   = (const float*)d_in[3];
    float*       out  = (float*)d_out;

    unsigned short* wt   = (unsigned short*)d_ws;                       // 229376 B
    float*          bias = (float*)((char*)d_ws + (size_t)TP * Fn * 2); // +448 B

    rf_prep<<<TP, 64, 0, stream>>>(fidx, fthr, fw, wt, bias);
    rf_gemm<<<GRID, BLOCK, 0, stream>>>(x, wt, bias, out);
}